// Round 1
// baseline (127.091 us; speedup 1.0000x reference)
//
#include <hip/hip_runtime.h>
#include <stdint.h>

#define N 8192
#define MAX_E (64 * N)          // 524288
#define TILE 2048
#define ROWS_PER_WAVE 4
#define WAVES_PER_BLOCK 4
#define ROWS_PER_BLOCK (ROWS_PER_WAVE * WAVES_PER_BLOCK)  // 16
#define NBLOCKS (N / ROWS_PER_BLOCK)                       // 512

// Exact replication of numpy f32: sum(pos*pos, -1) = ((x*x)+(y*y))+(z*z),
// each product rounded (no fma).
__device__ __forceinline__ float sq_exact(float x, float y, float z) {
    return __fadd_rn(__fadd_rn(__fmul_rn(x, x), __fmul_rn(y, y)), __fmul_rn(z, z));
}

// Exact replication of sgemm K=3 fma chain + gram identity + sqrt<5 compare.
// dist = sqrt(max(d2,0)) < 5.0f  <=>  d2 < 0x1.8ffffep+4f  (largest f32 below 25
// rounds to exactly 5.0 under correctly-rounded sqrtf, so it is excluded).
__device__ __forceinline__ bool edge_pred(float xi, float yi, float zi, float sqi,
                                          float xj, float yj, float zj, float sqj) {
    float dot = __fmaf_rn(zi, zj, __fmaf_rn(yi, yj, __fmul_rn(xi, xj)));
    float d2  = __fsub_rn(__fadd_rn(sqi, sqj), __fmul_rn(2.0f, dot));
    return d2 < 0x1.8ffffep+4f;
}

__global__ __launch_bounds__(256) void fill_kernel(int4* __restrict__ out, int n4) {
    int idx = blockIdx.x * blockDim.x + threadIdx.x;
    if (idx < n4) out[idx] = make_int4(-1, -1, -1, -1);
}

__global__ __launch_bounds__(256) void count_kernel(const float* __restrict__ posf,
                                                    int* __restrict__ counts) {
    __shared__ float xs[TILE], ys[TILE], zs[TILE], sqs[TILE];
    const int tid  = threadIdx.x;
    const int wave = tid >> 6;
    const int lane = tid & 63;
    const int row0 = blockIdx.x * ROWS_PER_BLOCK + wave * ROWS_PER_WAVE;

    float xi[ROWS_PER_WAVE], yi[ROWS_PER_WAVE], zi[ROWS_PER_WAVE], sqi[ROWS_PER_WAVE];
    int cnt[ROWS_PER_WAVE];
#pragma unroll
    for (int r = 0; r < ROWS_PER_WAVE; r++) {
        int i = row0 + r;
        xi[r] = posf[3 * i + 0];
        yi[r] = posf[3 * i + 1];
        zi[r] = posf[3 * i + 2];
        sqi[r] = sq_exact(xi[r], yi[r], zi[r]);
        cnt[r] = 0;
    }

    for (int tb = 0; tb < N; tb += TILE) {
        __syncthreads();
        for (int k = tid; k < TILE; k += 256) {
            float x = posf[3 * (tb + k) + 0];
            float y = posf[3 * (tb + k) + 1];
            float z = posf[3 * (tb + k) + 2];
            xs[k] = x; ys[k] = y; zs[k] = z;
            sqs[k] = sq_exact(x, y, z);
        }
        __syncthreads();
        for (int c = 0; c < TILE; c += 64) {
            int j = tb + c + lane;
            float xj = xs[c + lane], yj = ys[c + lane], zj = zs[c + lane], sqj = sqs[c + lane];
#pragma unroll
            for (int r = 0; r < ROWS_PER_WAVE; r++) {
                bool p = edge_pred(xi[r], yi[r], zi[r], sqi[r], xj, yj, zj, sqj)
                         && (j != row0 + r);
                cnt[r] += p ? 1 : 0;
            }
        }
    }
#pragma unroll
    for (int r = 0; r < ROWS_PER_WAVE; r++) {
        int v = cnt[r];
        for (int o = 32; o > 0; o >>= 1) v += __shfl_down(v, o);
        if (lane == 0) counts[row0 + r] = v;
    }
}

__global__ __launch_bounds__(256) void scan_kernel(const int* __restrict__ counts,
                                                   int* __restrict__ offsets) {
    __shared__ int part[256];
    const int t = threadIdx.x;
    int local[32];
    int s = 0;
#pragma unroll
    for (int k = 0; k < 32; k++) { local[k] = counts[t * 32 + k]; s += local[k]; }
    part[t] = s;
    __syncthreads();
    // Hillis-Steele inclusive scan over 256 partials
    for (int off = 1; off < 256; off <<= 1) {
        int v = (t >= off) ? part[t - off] : 0;
        __syncthreads();
        part[t] += v;
        __syncthreads();
    }
    int run = (t > 0) ? part[t - 1] : 0;  // exclusive base
#pragma unroll
    for (int k = 0; k < 32; k++) { offsets[t * 32 + k] = run; run += local[k]; }
}

__global__ __launch_bounds__(256) void emit_kernel(const float* __restrict__ posf,
                                                   const int* __restrict__ offsets,
                                                   int* __restrict__ out) {
    __shared__ float xs[TILE], ys[TILE], zs[TILE], sqs[TILE];
    const int tid  = threadIdx.x;
    const int wave = tid >> 6;
    const int lane = tid & 63;
    const int row0 = blockIdx.x * ROWS_PER_BLOCK + wave * ROWS_PER_WAVE;
    const uint64_t lane_lt = (1ull << lane) - 1ull;

    float xi[ROWS_PER_WAVE], yi[ROWS_PER_WAVE], zi[ROWS_PER_WAVE], sqi[ROWS_PER_WAVE];
    int off[ROWS_PER_WAVE];
#pragma unroll
    for (int r = 0; r < ROWS_PER_WAVE; r++) {
        int i = row0 + r;
        xi[r] = posf[3 * i + 0];
        yi[r] = posf[3 * i + 1];
        zi[r] = posf[3 * i + 2];
        sqi[r] = sq_exact(xi[r], yi[r], zi[r]);
        off[r] = offsets[i];
    }

    for (int tb = 0; tb < N; tb += TILE) {
        __syncthreads();
        for (int k = tid; k < TILE; k += 256) {
            float x = posf[3 * (tb + k) + 0];
            float y = posf[3 * (tb + k) + 1];
            float z = posf[3 * (tb + k) + 2];
            xs[k] = x; ys[k] = y; zs[k] = z;
            sqs[k] = sq_exact(x, y, z);
        }
        __syncthreads();
        for (int c = 0; c < TILE; c += 64) {
            int j = tb + c + lane;
            float xj = xs[c + lane], yj = ys[c + lane], zj = zs[c + lane], sqj = sqs[c + lane];
#pragma unroll
            for (int r = 0; r < ROWS_PER_WAVE; r++) {
                bool p = edge_pred(xi[r], yi[r], zi[r], sqi[r], xj, yj, zj, sqj)
                         && (j != row0 + r);
                uint64_t m = __ballot(p);
                if (p) {
                    int slot = off[r] + __popcll(m & lane_lt);
                    if (slot < MAX_E) {
                        out[slot]         = row0 + r;  // rows
                        out[MAX_E + slot] = j;         // cols
                    }
                }
                off[r] += __popcll(m);
            }
        }
    }
}

extern "C" void kernel_launch(void* const* d_in, const int* in_sizes, int n_in,
                              void* d_out, int out_size, void* d_ws, size_t ws_size,
                              hipStream_t stream) {
    const float* posf = (const float*)d_in[0];
    int* out = (int*)d_out;
    int* counts  = (int*)d_ws;
    int* offsets = counts + N;

    const int n4 = (2 * MAX_E) / 4;
    fill_kernel<<<(n4 + 255) / 256, 256, 0, stream>>>((int4*)out, n4);
    count_kernel<<<NBLOCKS, 256, 0, stream>>>(posf, counts);
    scan_kernel<<<1, 256, 0, stream>>>(counts, offsets);
    emit_kernel<<<NBLOCKS, 256, 0, stream>>>(posf, offsets, out);
}

// Round 2
// 90.337 us; speedup vs baseline: 1.4068x; 1.4068x over previous
//
#include <hip/hip_runtime.h>
#include <stdint.h>

#define N 8192
#define MAX_E (64 * N)          // 524288
#define NCHUNK (N / 64)         // 128 mask chunks per row
#define TILE 2048
#define A_ROWS_PER_WAVE 2
#define A_WAVES 4
#define A_ROWS_PER_BLOCK (A_ROWS_PER_WAVE * A_WAVES)  // 8
#define A_NBLOCKS (N / A_ROWS_PER_BLOCK)              // 1024

// Exact replication of numpy f32: sum(pos*pos, -1) = ((x*x)+(y*y))+(z*z),
// each product rounded (no fma).
__device__ __forceinline__ float sq_exact(float x, float y, float z) {
    return __fadd_rn(__fadd_rn(__fmul_rn(x, x), __fmul_rn(y, y)), __fmul_rn(z, z));
}

// d2 = RN(sqsum - RN(2*dot)); since 2*dot is exact, fma(-2,dot,sqsum) is
// bit-identical and saves one op. dist<5 <=> d2 < 0x1.8ffffep+4f (largest
// f32 below 25 has sqrt rounding to exactly 5.0, so it must be excluded).
__device__ __forceinline__ bool edge_pred(float xi, float yi, float zi, float sqi,
                                          const float4& pj) {
    float dot = __fmaf_rn(zi, pj.z, __fmaf_rn(yi, pj.y, __fmul_rn(xi, pj.x)));
    float d2  = __fmaf_rn(-2.0f, dot, __fadd_rn(sqi, pj.w));
    return d2 < 0x1.8ffffep+4f;
}

__global__ __launch_bounds__(256) void fill_kernel(int4* __restrict__ out, int n4) {
    int idx = blockIdx.x * blockDim.x + threadIdx.x;
    if (idx < n4) out[idx] = make_int4(-1, -1, -1, -1);
}

// Pass 1: full N^2 predicate -> 64-bit ballot masks (lane l owns chunks 2l,2l+1
// of each of its rows) + per-row counts. Self-edge cleared via post-loop bit fixup
// (d2_self ~ 0 < 25 always, so the predicate always fires on the diagonal).
__global__ __launch_bounds__(256) void mask_kernel(const float* __restrict__ posf,
                                                   uint64_t* __restrict__ masks,
                                                   int* __restrict__ counts) {
    __shared__ float4 pts[TILE];
    const int tid  = threadIdx.x;
    const int wave = tid >> 6;
    const int lane = tid & 63;
    const int row0 = blockIdx.x * A_ROWS_PER_BLOCK + wave * A_ROWS_PER_WAVE;

    float xi[A_ROWS_PER_WAVE], yi[A_ROWS_PER_WAVE], zi[A_ROWS_PER_WAVE], sqi[A_ROWS_PER_WAVE];
    uint64_t k0[A_ROWS_PER_WAVE], k1[A_ROWS_PER_WAVE];
#pragma unroll
    for (int r = 0; r < A_ROWS_PER_WAVE; r++) {
        int i = row0 + r;
        xi[r] = posf[3 * i + 0];
        yi[r] = posf[3 * i + 1];
        zi[r] = posf[3 * i + 2];
        sqi[r] = sq_exact(xi[r], yi[r], zi[r]);
        k0[r] = 0; k1[r] = 0;
    }

    for (int tb = 0; tb < N; tb += TILE) {
        __syncthreads();
        for (int k = tid; k < TILE; k += 256) {
            float x = posf[3 * (tb + k) + 0];
            float y = posf[3 * (tb + k) + 1];
            float z = posf[3 * (tb + k) + 2];
            pts[k] = make_float4(x, y, z, sq_exact(x, y, z));
        }
        __syncthreads();
        // process chunk-pairs: owner lane = global chunk-pair index & 63
#pragma unroll 4
        for (int c = 0; c < TILE; c += 128) {
            const int owner = ((tb + c) >> 7) & 63;
            float4 pa = pts[c + lane];
            float4 pb = pts[c + 64 + lane];
#pragma unroll
            for (int r = 0; r < A_ROWS_PER_WAVE; r++) {
                uint64_t ma = __ballot(edge_pred(xi[r], yi[r], zi[r], sqi[r], pa));
                if (lane == owner) k0[r] = ma;
                uint64_t mb = __ballot(edge_pred(xi[r], yi[r], zi[r], sqi[r], pb));
                if (lane == owner) k1[r] = mb;
            }
        }
    }

#pragma unroll
    for (int r = 0; r < A_ROWS_PER_WAVE; r++) {
        const int row = row0 + r;
        // clear the self bit: chunk = row>>6, owner lane = chunk>>1, slot = chunk&1
        const int gs = row >> 6;
        if (lane == (gs >> 1)) {
            uint64_t clr = ~(1ull << (row & 63));
            if (gs & 1) k1[r] &= clr; else k0[r] &= clr;
        }
        ulonglong2 v; v.x = k0[r]; v.y = k1[r];
        ((ulonglong2*)(masks + (size_t)row * NCHUNK))[lane] = v;
        int t = __popcll(k0[r]) + __popcll(k1[r]);
#pragma unroll
        for (int o = 32; o > 0; o >>= 1) t += __shfl_down(t, o);
        if (lane == 0) counts[row] = t;
    }
}

__global__ __launch_bounds__(256) void scan_kernel(const int* __restrict__ counts,
                                                   int* __restrict__ offsets) {
    __shared__ int part[256];
    const int t = threadIdx.x;
    int local[32];
    int s = 0;
#pragma unroll
    for (int k = 0; k < 32; k++) { local[k] = counts[t * 32 + k]; s += local[k]; }
    part[t] = s;
    __syncthreads();
    for (int off = 1; off < 256; off <<= 1) {
        int v = (t >= off) ? part[t - off] : 0;
        __syncthreads();
        part[t] += v;
        __syncthreads();
    }
    int run = (t > 0) ? part[t - 1] : 0;  // exclusive base
#pragma unroll
    for (int k = 0; k < 32; k++) { offsets[t * 32 + k] = run; run += local[k]; }
}

// Pass 2: masks -> ordered edge list. One wave per row; lane l holds chunks
// 2l,2l+1; wave-exclusive-scan of popcounts gives in-order slots.
__global__ __launch_bounds__(256) void emit_kernel(const uint64_t* __restrict__ masks,
                                                   const int* __restrict__ offsets,
                                                   int* __restrict__ out) {
    const int wave = threadIdx.x >> 6;
    const int lane = threadIdx.x & 63;
    const int row  = blockIdx.x * 4 + wave;

    ulonglong2 v = ((const ulonglong2*)(masks + (size_t)row * NCHUNK))[lane];
    int s0 = __popcll(v.x), s1 = __popcll(v.y);
    int x = s0 + s1;
#pragma unroll
    for (int o = 1; o < 64; o <<= 1) {
        int t = __shfl_up(x, o);
        if (lane >= o) x += t;
    }
    int slot = offsets[row] + (x - (s0 + s1));  // exclusive prefix

    const int col0 = lane * 128;  // chunk 2*lane covers cols [128*lane, 128*lane+64)
    uint64_t m = v.x;
    while (m) {
        int b = __ffsll((unsigned long long)m) - 1;
        m &= m - 1;
        if (slot < MAX_E) { out[slot] = row; out[MAX_E + slot] = col0 + b; }
        slot++;
    }
    m = v.y;
    while (m) {
        int b = __ffsll((unsigned long long)m) - 1;
        m &= m - 1;
        if (slot < MAX_E) { out[slot] = row; out[MAX_E + slot] = col0 + 64 + b; }
        slot++;
    }
}

extern "C" void kernel_launch(void* const* d_in, const int* in_sizes, int n_in,
                              void* d_out, int out_size, void* d_ws, size_t ws_size,
                              hipStream_t stream) {
    const float* posf = (const float*)d_in[0];
    int* out = (int*)d_out;
    int* counts  = (int*)d_ws;
    int* offsets = counts + N;
    uint64_t* masks = (uint64_t*)((char*)d_ws + 65536);  // 8 MB

    const int n4 = (2 * MAX_E) / 4;
    fill_kernel<<<(n4 + 255) / 256, 256, 0, stream>>>((int4*)out, n4);
    mask_kernel<<<A_NBLOCKS, 256, 0, stream>>>(posf, masks, counts);
    scan_kernel<<<1, 256, 0, stream>>>(counts, offsets);
    emit_kernel<<<N / 4, 256, 0, stream>>>(masks, offsets, out);
}

// Round 4
// 87.693 us; speedup vs baseline: 1.4493x; 1.0302x over previous
//
#include <hip/hip_runtime.h>
#include <stdint.h>

#define N 8192
#define MAX_E (64 * N)          // 524288
#define NCHUNK (N / 64)         // 128 mask chunks per row
#define TILE 2048
#define A_ROWS_PER_WAVE 4
#define A_WAVES 4
#define A_ROWS_PER_BLOCK (A_ROWS_PER_WAVE * A_WAVES)  // 16
#define A_NBLOCKS (N / A_ROWS_PER_BLOCK)              // 512

// Exact replication of numpy f32: sum(pos*pos, -1) = ((x*x)+(y*y))+(z*z),
// each product rounded (no fma).
__device__ __forceinline__ float sq_exact(float x, float y, float z) {
    return __fadd_rn(__fadd_rn(__fmul_rn(x, x), __fmul_rn(y, y)), __fmul_rn(z, z));
}

// d2 = RN(sqsum - RN(2*dot)); 2*dot is exact so fma(-2,dot,sqsum) is bit-identical.
// dist<5 <=> d2 < 0x1.8ffffep+4f (largest f32 below 25 has correctly-rounded sqrt
// equal to exactly 5.0, so that value must be excluded).
__device__ __forceinline__ bool edge_pred(float xi, float yi, float zi, float sqi,
                                          const float4& pj) {
    float dot = __fmaf_rn(zi, pj.z, __fmaf_rn(yi, pj.y, __fmul_rn(xi, pj.x)));
    float d2  = __fmaf_rn(-2.0f, dot, __fadd_rn(sqi, pj.w));
    return d2 < 0x1.8ffffep+4f;
}

// Pass 1: full N^2 predicate -> 64-bit ballot masks (lane l owns chunks 2l,2l+1
// of each of its rows) + per-row counts. Self-edge cleared via post-loop bit fixup.
__global__ __launch_bounds__(256) void mask_kernel(const float* __restrict__ posf,
                                                   uint64_t* __restrict__ masks,
                                                   int* __restrict__ counts) {
    __shared__ float4 pts[TILE];
    const int tid  = threadIdx.x;
    const int wave = tid >> 6;
    const int lane = tid & 63;
    const int row0 = blockIdx.x * A_ROWS_PER_BLOCK + wave * A_ROWS_PER_WAVE;

    float xi[A_ROWS_PER_WAVE], yi[A_ROWS_PER_WAVE], zi[A_ROWS_PER_WAVE], sqi[A_ROWS_PER_WAVE];
    uint64_t k0[A_ROWS_PER_WAVE], k1[A_ROWS_PER_WAVE];
#pragma unroll
    for (int r = 0; r < A_ROWS_PER_WAVE; r++) {
        int i = row0 + r;
        xi[r] = posf[3 * i + 0];
        yi[r] = posf[3 * i + 1];
        zi[r] = posf[3 * i + 2];
        sqi[r] = sq_exact(xi[r], yi[r], zi[r]);
        k0[r] = 0; k1[r] = 0;
    }

    for (int tb = 0; tb < N; tb += TILE) {
        __syncthreads();
        for (int k = tid; k < TILE; k += 256) {
            float x = posf[3 * (tb + k) + 0];
            float y = posf[3 * (tb + k) + 1];
            float z = posf[3 * (tb + k) + 2];
            pts[k] = make_float4(x, y, z, sq_exact(x, y, z));
        }
        __syncthreads();
#pragma unroll 4
        for (int c = 0; c < TILE; c += 128) {
            const int owner = ((tb + c) >> 7) & 63;  // wave-uniform
            float4 pa = pts[c + lane];
            float4 pb = pts[c + 64 + lane];
#pragma unroll
            for (int r = 0; r < A_ROWS_PER_WAVE; r++) {
                uint64_t ma = __ballot(edge_pred(xi[r], yi[r], zi[r], sqi[r], pa));
                if (lane == owner) k0[r] = ma;
                uint64_t mb = __ballot(edge_pred(xi[r], yi[r], zi[r], sqi[r], pb));
                if (lane == owner) k1[r] = mb;
            }
        }
    }

#pragma unroll
    for (int r = 0; r < A_ROWS_PER_WAVE; r++) {
        const int row = row0 + r;
        // clear the self bit: chunk = row>>6, owner lane = chunk>>1, slot = chunk&1
        const int gs = row >> 6;
        if (lane == (gs >> 1)) {
            uint64_t clr = ~(1ull << (row & 63));
            if (gs & 1) k1[r] &= clr; else k0[r] &= clr;
        }
        ulonglong2 v; v.x = k0[r]; v.y = k1[r];
        ((ulonglong2*)(masks + (size_t)row * NCHUNK))[lane] = v;
        int t = __popcll(k0[r]) + __popcll(k1[r]);
#pragma unroll
        for (int o = 32; o > 0; o >>= 1) t += __shfl_down(t, o);
        if (lane == 0) counts[row] = t;
    }
}

__global__ __launch_bounds__(256) void scan_kernel(const int* __restrict__ counts,
                                                   int* __restrict__ offsets) {
    __shared__ int part[256];
    const int t = threadIdx.x;
    int local[32];
    int s = 0;
#pragma unroll
    for (int k = 0; k < 32; k++) { local[k] = counts[t * 32 + k]; s += local[k]; }
    part[t] = s;
    __syncthreads();
    for (int off = 1; off < 256; off <<= 1) {
        int v = (t >= off) ? part[t - off] : 0;
        __syncthreads();
        part[t] += v;
        __syncthreads();
    }
    int run = (t > 0) ? part[t - 1] : 0;  // exclusive base
#pragma unroll
    for (int k = 0; k < 32; k++) { offsets[t * 32 + k] = run; run += local[k]; }
    if (t == 255) offsets[N] = part[255];  // total edge count
}

// Pass 2: masks -> ordered edge list + tail fill with -1.
// One wave per row; lane l holds chunks 2l,2l+1; wave-exclusive-scan of
// popcounts gives in-order slots.
__global__ __launch_bounds__(256) void emit_kernel(const uint64_t* __restrict__ masks,
                                                   const int* __restrict__ offsets,
                                                   int* __restrict__ out) {
    const int wave = threadIdx.x >> 6;
    const int lane = threadIdx.x & 63;
    const int row  = blockIdx.x * 4 + wave;

    // tail fill: slots [E, MAX_E) of both halves get -1. 524288 threads cover
    // the <=262K tail slots with one conditional store pair each.
    {
        const int E = offsets[N];
        const int idx = E + blockIdx.x * 256 + threadIdx.x;
        if (idx < MAX_E) { out[idx] = -1; out[MAX_E + idx] = -1; }
    }

    ulonglong2 v = ((const ulonglong2*)(masks + (size_t)row * NCHUNK))[lane];
    int s0 = __popcll(v.x), s1 = __popcll(v.y);
    int x = s0 + s1;
#pragma unroll
    for (int o = 1; o < 64; o <<= 1) {
        int t = __shfl_up(x, o);
        if (lane >= o) x += t;
    }
    int slot = offsets[row] + (x - (s0 + s1));  // exclusive prefix within row

    const int col0 = lane * 128;  // chunk 2*lane covers cols [128*lane, 128*lane+64)
    uint64_t m = v.x;
    while (m) {
        int b = __ffsll((unsigned long long)m) - 1;
        m &= m - 1;
        if (slot < MAX_E) { out[slot] = row; out[MAX_E + slot] = col0 + b; }
        slot++;
    }
    m = v.y;
    while (m) {
        int b = __ffsll((unsigned long long)m) - 1;
        m &= m - 1;
        if (slot < MAX_E) { out[slot] = row; out[MAX_E + slot] = col0 + 64 + b; }
        slot++;
    }
}

extern "C" void kernel_launch(void* const* d_in, const int* in_sizes, int n_in,
                              void* d_out, int out_size, void* d_ws, size_t ws_size,
                              hipStream_t stream) {
    const float* posf = (const float*)d_in[0];
    int* out = (int*)d_out;
    int* counts  = (int*)d_ws;                         // N ints
    int* offsets = counts + N;                         // N+1 ints
    uint64_t* masks = (uint64_t*)((char*)d_ws + (128 << 10));  // 8 MB at 128KB offset

    mask_kernel<<<A_NBLOCKS, 256, 0, stream>>>(posf, masks, counts);
    scan_kernel<<<1, 256, 0, stream>>>(counts, offsets);
    emit_kernel<<<N / 4, 256, 0, stream>>>(masks, offsets, out);
}